// Round 5
// baseline (3028.373 us; speedup 1.0000x reference)
//
#include <hip/hip_runtime.h>
#include <math.h>

// Problem constants
constexpr int KDIM  = 784;   // feature dim
constexpr int NA    = 30;    // number of angles
constexpr int ROWS  = 64;    // rows per block (= lanes per wave)
constexpr int NW    = 4;     // waves per block (K-split)
constexpr int NT    = 256;   // threads per block
constexpr int RCOLS = 128;   // columns staged per round = NW * 32
constexpr int NRND  = 6;     // full rounds: 6*128 = 768
constexpr int KTAIL = 16;    // 784 - 768

__global__ __launch_bounds__(NT, 4)   // 4 blocks/CU -> 16 waves/CU, 128-VGPR cap
void fused_rnn_circuit(const float* __restrict__ X,
                       const float* __restrict__ W,
                       const float* __restrict__ Bv,
                       float* __restrict__ out)
{
    const int t    = threadIdx.x;
    const int lane = t & 63;
    const int w    = t >> 6;                 // wave id 0..3
    const long long row0 = (long long)blockIdx.x * ROWS;

    // One 32 KB tile: 4 chunks x 64 rows x 32 cols. Slot (16B) s = cc*512 + row*8 + p,
    // slot p within a row stores global colblock g = p ^ (row&7)  [XOR swizzle].
    // Re-used after the K-loop as part[4][64][32] for the cross-wave reduction.
    __shared__ float xs[ROWS * RCOLS];

    // ---- staging geometry: 8 global_load_lds per thread per round ----
    const int srow = t >> 3;                 // 0..31
    const int p8   = t & 7;
    const int g    = p8 ^ (srow & 7);        // swizzled source colblock (involution)

    auto stage = [&](int j) {
#pragma unroll
        for (int i = 0; i < 8; ++i) {
            const int row = ((i & 1) << 5) + srow;   // 0..63
            const int cc  = i >> 1;                  // chunk 0..3
            const float* gp = X + (row0 + row) * (long long)KDIM + j * RCOLS + cc * 32 + g * 4;
            float* lp = &xs[i * 1024 + w * 256];     // wave-uniform base; HW adds lane*16B
            __builtin_amdgcn_global_load_lds(
                (const __attribute__((address_space(1))) void*)gp,
                (__attribute__((address_space(3))) void*)lp, 16, 0, 0);
        }
    };

    const int r  = lane;                     // this thread's row
    const int rx = r & 7;

    float acc[NA];
#pragma unroll
    for (int a = 0; a < NA; ++a) acc[a] = 0.f;

    // prologue
    stage(0);
    __syncthreads();

    // ---- K loop: wave w consumes chunk w of each round (cols j*128+32w .. +32) ----
    for (int j = 0; j < NRND; ++j) {
        float xv[32];
#pragma unroll
        for (int q = 0; q < 8; ++q) {
            float4 v = *reinterpret_cast<const float4*>(
                &xs[w * 2048 + r * 32 + ((q ^ rx) << 2)]);
            xv[4 * q + 0] = v.x; xv[4 * q + 1] = v.y;
            xv[4 * q + 2] = v.z; xv[4 * q + 3] = v.w;
        }
        const float* wb = W + j * RCOLS + w * 32;     // wave-uniform -> s_load
#pragma unroll
        for (int a = 0; a < NA; ++a) {
            const float* wr = wb + (long long)a * KDIM;
            float s = acc[a];
#pragma unroll
            for (int k = 0; k < 32; ++k) s = fmaf(xv[k], wr[k], s);
            acc[a] = s;
        }
        __syncthreads();                              // all waves done reading tile j
        if (j + 1 < NRND) { stage(j + 1); __syncthreads(); }
    }

    // ---- tail: 64 rows x 16 cols = 4 KB, single staged issue, wave 0 computes ----
    {
        const float* gp = X + (row0 + (t >> 2)) * (long long)KDIM + NRND * RCOLS + (t & 3) * 4;
        float* lp = &xs[w * 256];
        __builtin_amdgcn_global_load_lds(
            (const __attribute__((address_space(1))) void*)gp,
            (__attribute__((address_space(3))) void*)lp, 16, 0, 0);
    }
    __syncthreads();
    if (w == 0) {
        float xv[KTAIL];
#pragma unroll
        for (int q = 0; q < 4; ++q) {
            float4 v = *reinterpret_cast<const float4*>(&xs[r * 16 + q * 4]);
            xv[4 * q + 0] = v.x; xv[4 * q + 1] = v.y;
            xv[4 * q + 2] = v.z; xv[4 * q + 3] = v.w;
        }
        const float* wb = W + NRND * RCOLS;
#pragma unroll
        for (int a = 0; a < NA; ++a) {
            const float* wr = wb + (long long)a * KDIM;
            float s = acc[a];
#pragma unroll
            for (int k = 0; k < KTAIL; ++k) s = fmaf(xv[k], wr[k], s);
            acc[a] = s;
        }
    }
    __syncthreads();   // tail data consumed; tile free for reduction reuse

    // ---- write partials (swizzled, b128): part[w][r][ab] at xs[w*2048 + r*32 + (ab^rx)*4] ----
    {
        float accp[32];
#pragma unroll
        for (int a = 0; a < 32; ++a) accp[a] = (a < NA) ? acc[a] : 0.f;
#pragma unroll
        for (int ab = 0; ab < 8; ++ab) {
            float4 v = make_float4(accp[4 * ab + 0], accp[4 * ab + 1],
                                   accp[4 * ab + 2], accp[4 * ab + 3]);
            *reinterpret_cast<float4*>(&xs[w * 2048 + r * 32 + ((ab ^ rx) << 2)]) = v;
        }
    }
    __syncthreads();

    // ---- wave 0: reduce partials, add bias, simulate circuit, store ----
    if (t < 64) {
        float red[32];
#pragma unroll
        for (int i = 0; i < 32; ++i) red[i] = 0.f;
#pragma unroll
        for (int ww = 0; ww < NW; ++ww) {
#pragma unroll
            for (int ab = 0; ab < 8; ++ab) {
                float4 v = *reinterpret_cast<const float4*>(
                    &xs[ww * 2048 + r * 32 + ((ab ^ rx) << 2)]);
                red[4 * ab + 0] += v.x; red[4 * ab + 1] += v.y;
                red[4 * ab + 2] += v.z; red[4 * ab + 3] += v.w;
            }
        }
        float ap[NA];
#pragma unroll
        for (int a = 0; a < NA; ++a) ap[a] = red[a] + Bv[a];   // Bv uniform -> s_load

        float sr[16], si[16];
#pragma unroll
        for (int q = 0; q < 16; ++q) { sr[q] = 0.f; si[q] = 0.f; }
        sr[0] = 1.f;

        auto u3 = [&](int wq, float th, float ph, float la) {
            float ch, sh;  __sincosf(0.5f * th, &sh, &ch);
            float elr, eli; __sincosf(la, &eli, &elr);
            float epr, epi; __sincosf(ph, &epi, &epr);
            float eer = epr * elr - epi * eli;   // ep*el
            float eei = epr * eli + epi * elr;
            const int m = 1 << (3 - wq);
#pragma unroll
            for (int idx = 0; idx < 16; ++idx) {
                if (idx & m) continue;
                int i1 = idx + m;
                float o0r = sr[idx], o0i = si[idx], o1r = sr[i1], o1i = si[i1];
                float e1r = elr * o1r - eli * o1i;
                float e1i = elr * o1i + eli * o1r;
                sr[idx] = ch * o0r - sh * e1r;
                si[idx] = ch * o0i - sh * e1i;
                float p0r = epr * o0r - epi * o0i;
                float p0i = epr * o0i + epi * o0r;
                float q1r = eer * o1r - eei * o1i;
                float q1i = eer * o1i + eei * o1r;
                sr[i1] = sh * p0r + ch * q1r;
                si[i1] = sh * p0i + ch * q1i;
            }
        };

#pragma unroll
        for (int lay = 0; lay < 2; ++lay) {
            const int base = lay * 15;
#pragma unroll
            for (int i = 0; i < 3; ++i) {
                {
                    float th = ap[base + i * 4];
                    float ch, sh; __sincosf(0.5f * th, &sh, &ch);
                    const int m1 = 1 << (3 - i);
                    const int m2 = 1 << (2 - i);
#pragma unroll
                    for (int b0 = 0; b0 < 16; ++b0) {
                        if (b0 & (m1 | m2)) continue;
                        int i00 = b0, i01 = b0 + m2, i10 = b0 + m1, i11 = b0 + m1 + m2;
                        float o00r = sr[i00], o00i = si[i00], o11r = sr[i11], o11i = si[i11];
                        sr[i00] = ch * o00r + sh * o11i;
                        si[i00] = ch * o00i - sh * o11r;
                        sr[i11] = ch * o11r + sh * o00i;
                        si[i11] = ch * o11i - sh * o00r;
                        float o01r = sr[i01], o01i = si[i01], o10r = sr[i10], o10i = si[i10];
                        sr[i01] = ch * o01r + sh * o10i;
                        si[i01] = ch * o01i - sh * o10r;
                        sr[i10] = ch * o10r + sh * o01i;
                        si[i10] = ch * o10i - sh * o01r;
                    }
                }
                u3(i, ap[base + i * 4 + 1], ap[base + i * 4 + 2], ap[base + i * 4 + 3]);
            }
            u3(3, ap[base + 12], ap[base + 13], ap[base + 14]);
        }

        float* orow = out + (row0 + r) * 32;
#pragma unroll
        for (int q = 0; q < 8; ++q) {
            float4 v = make_float4(sr[2 * q], si[2 * q], sr[2 * q + 1], si[2 * q + 1]);
            *reinterpret_cast<float4*>(orow + q * 4) = v;
        }
    }
}

extern "C" void kernel_launch(void* const* d_in, const int* in_sizes, int n_in,
                              void* d_out, int out_size, void* d_ws, size_t ws_size,
                              hipStream_t stream) {
    const float* X  = (const float*)d_in[0];
    const float* W  = (const float*)d_in[1];
    const float* Bv = (const float*)d_in[2];
    float* out = (float*)d_out;

    const int Bn = in_sizes[0] / KDIM;   // 65536
    dim3 grid(Bn / ROWS);                // 1024 blocks x 256 threads, 4 blocks/CU
    fused_rnn_circuit<<<grid, NT, 0, stream>>>(X, W, Bv, out);
}

// Round 6
// 147.691 us; speedup vs baseline: 20.5047x; 20.5047x over previous
//
#include <hip/hip_runtime.h>
#include <math.h>

// Problem constants
constexpr int KDIM  = 784;   // feature dim
constexpr int NA    = 30;    // number of angles
constexpr int ROWS  = 64;    // rows per block (= lanes per wave)
constexpr int NW    = 4;     // waves per block (K-split)
constexpr int NT    = 256;   // threads per block
constexpr int RC    = 64;    // columns staged per round (= NW * 16)
constexpr int NRND  = 12;    // full rounds: 12*64 = 768
constexpr int KTAIL = 16;    // 784 - 768

__global__ __launch_bounds__(NT)   // NO min-occupancy arg: avoid the 64-VGPR cap / spill
void fused_rnn_circuit(const float* __restrict__ X,
                       const float* __restrict__ W,
                       const float* __restrict__ Bv,
                       float* __restrict__ out)
{
    const int t    = threadIdx.x;
    const int lane = t & 63;
    const int w    = t >> 6;                         // wave id 0..3
    const int w_u  = __builtin_amdgcn_readfirstlane(w);   // provably wave-uniform
    const long long row0 = (long long)blockIdx.x * ROWS;

    // Double-buffered round tile: 64 rows x 64 cols x 2 = 32 KB.
    // Slot (16B) s = row*16 + p ; position p stores global colblock
    // g = (p&8) | ((p&7) ^ (row&7))   [XOR swizzle, involution]
    // After the K-loop the 32 KB is re-used as part[4][64][32] for reduction.
    __shared__ float xs[2][ROWS * RC];
    float* const xsf = &xs[0][0];                    // flat 8192-float view

    // ---- staging geometry: 1024 slots/round, 256 threads -> 4 global_load_lds ----
    // call i covers slots i*256 + t : row = i*16 + (t>>4), p = t&15
    const int srow16 = t >> 4;                       // 0..15
    const int p      = t & 15;
    const int g      = (p & 8) | ((p & 7) ^ (srow16 & 7));
    const float* gbase0 = X + (row0 +  0 + srow16) * (long long)KDIM + g * 4;
    const float* gbase1 = X + (row0 + 16 + srow16) * (long long)KDIM + g * 4;
    const float* gbase2 = X + (row0 + 32 + srow16) * (long long)KDIM + g * 4;
    const float* gbase3 = X + (row0 + 48 + srow16) * (long long)KDIM + g * 4;

    auto stage = [&](int j, int buf) {
        const int off = j * RC;
        __builtin_amdgcn_global_load_lds(
            (const __attribute__((address_space(1))) void*)(gbase0 + off),
            (__attribute__((address_space(3))) void*)&xs[buf][0 * 1024 + w * 256], 16, 0, 0);
        __builtin_amdgcn_global_load_lds(
            (const __attribute__((address_space(1))) void*)(gbase1 + off),
            (__attribute__((address_space(3))) void*)&xs[buf][1 * 1024 + w * 256], 16, 0, 0);
        __builtin_amdgcn_global_load_lds(
            (const __attribute__((address_space(1))) void*)(gbase2 + off),
            (__attribute__((address_space(3))) void*)&xs[buf][2 * 1024 + w * 256], 16, 0, 0);
        __builtin_amdgcn_global_load_lds(
            (const __attribute__((address_space(1))) void*)(gbase3 + off),
            (__attribute__((address_space(3))) void*)&xs[buf][3 * 1024 + w * 256], 16, 0, 0);
    };
    // tail: 64 rows x 16 cols = 256 slots, 1 per thread: row = t>>2, c4 = t&3 (no swizzle)
    auto stage_tail = [&]() {
        const float* gp = X + (row0 + (t >> 2)) * (long long)KDIM + NRND * RC + (t & 3) * 4;
        __builtin_amdgcn_global_load_lds(
            (const __attribute__((address_space(1))) void*)gp,
            (__attribute__((address_space(3))) void*)&xs[0][w * 256], 16, 0, 0);
    };

    const int r  = lane;                             // this thread's row
    const int rx = r & 7;

    float acc[NA];
#pragma unroll
    for (int a = 0; a < NA; ++a) acc[a] = 0.f;

    // prologue
    stage(0, 0);
    __syncthreads();

    // ---- K loop: wave w consumes cols j*64 + w*16 .. +16 of each round ----
    for (int j = 0; j < NRND; ++j) {
        const int buf = j & 1;
        if (j + 1 < NRND) stage(j + 1, buf ^ 1);
        else              stage_tail();              // lands in xs[0][0..1023] (free region)

        float xv[16];
#pragma unroll
        for (int qq = 0; qq < 4; ++qq) {
            const int q  = 4 * w + qq;               // colblock 0..15
            const int pq = (q & 8) | ((q & 7) ^ rx); // stored position
            float4 v = *reinterpret_cast<const float4*>(&xs[buf][r * RC + pq * 4]);
            xv[4 * qq + 0] = v.x; xv[4 * qq + 1] = v.y;
            xv[4 * qq + 2] = v.z; xv[4 * qq + 3] = v.w;
        }

        const float* wb = W + j * RC + w_u * 16;     // scalar base -> s_load
#pragma unroll
        for (int a = 0; a < NA; ++a) {
            const float* wr = wb + (long long)a * KDIM;
            float s = acc[a];
#pragma unroll
            for (int k = 0; k < 16; ++k) s = fmaf(xv[k], wr[k], s);
            acc[a] = s;
        }
        __syncthreads();   // all waves done with tile j; next-tile loads drained
    }

    // ---- tail: wave 0 adds cols 768..783 (from xs[0][0..1023], already drained) ----
    if (w == 0) {
        float xv[KTAIL];
#pragma unroll
        for (int qq = 0; qq < 4; ++qq) {
            float4 v = *reinterpret_cast<const float4*>(&xsf[r * 16 + qq * 4]);
            xv[4 * qq + 0] = v.x; xv[4 * qq + 1] = v.y;
            xv[4 * qq + 2] = v.z; xv[4 * qq + 3] = v.w;
        }
        const float* wb = W + NRND * RC;
#pragma unroll
        for (int a = 0; a < NA; ++a) {
            const float* wr = wb + (long long)a * KDIM;
            float s = acc[a];
#pragma unroll
            for (int k = 0; k < KTAIL; ++k) s = fmaf(xv[k], wr[k], s);
            acc[a] = s;
        }
    }

    // ---- write partials: part[w][r][ab] at xsf[w*2048 + r*32 + (ab^rx)*4] ----
    // wave0 writes xsf[0..2047] (includes the tail region it just read: same wave,
    // program order -> safe). Waves 1..3 write disjoint regions.
    {
#pragma unroll
        for (int ab = 0; ab < 8; ++ab) {
            float4 v;
            v.x = (4 * ab + 0 < NA) ? acc[4 * ab + 0] : 0.f;
            v.y = (4 * ab + 1 < NA) ? acc[4 * ab + 1] : 0.f;
            v.z = (4 * ab + 2 < NA) ? acc[4 * ab + 2] : 0.f;
            v.w = (4 * ab + 3 < NA) ? acc[4 * ab + 3] : 0.f;
            *reinterpret_cast<float4*>(&xsf[w * 2048 + r * 32 + ((ab ^ rx) << 2)]) = v;
        }
    }
    __syncthreads();

    // ---- wave 0: reduce partials, add bias, simulate circuit, store ----
    if (t < 64) {
        float red[32];
#pragma unroll
        for (int i = 0; i < 32; ++i) red[i] = 0.f;
#pragma unroll
        for (int ww = 0; ww < NW; ++ww) {
#pragma unroll
            for (int ab = 0; ab < 8; ++ab) {
                float4 v = *reinterpret_cast<const float4*>(
                    &xsf[ww * 2048 + r * 32 + ((ab ^ rx) << 2)]);
                red[4 * ab + 0] += v.x; red[4 * ab + 1] += v.y;
                red[4 * ab + 2] += v.z; red[4 * ab + 3] += v.w;
            }
        }
        float ap[NA];
#pragma unroll
        for (int a = 0; a < NA; ++a) ap[a] = red[a] + Bv[a];   // uniform -> s_load

        float sr[16], si[16];
#pragma unroll
        for (int q = 0; q < 16; ++q) { sr[q] = 0.f; si[q] = 0.f; }
        sr[0] = 1.f;

        auto u3 = [&](int wq, float th, float ph, float la) {
            float ch, sh;  __sincosf(0.5f * th, &sh, &ch);
            float elr, eli; __sincosf(la, &eli, &elr);
            float epr, epi; __sincosf(ph, &epi, &epr);
            float eer = epr * elr - epi * eli;   // ep*el
            float eei = epr * eli + epi * elr;
            const int m = 1 << (3 - wq);
#pragma unroll
            for (int idx = 0; idx < 16; ++idx) {
                if (idx & m) continue;
                int i1 = idx + m;
                float o0r = sr[idx], o0i = si[idx], o1r = sr[i1], o1i = si[i1];
                float e1r = elr * o1r - eli * o1i;
                float e1i = elr * o1i + eli * o1r;
                sr[idx] = ch * o0r - sh * e1r;
                si[idx] = ch * o0i - sh * e1i;
                float p0r = epr * o0r - epi * o0i;
                float p0i = epr * o0i + epi * o0r;
                float q1r = eer * o1r - eei * o1i;
                float q1i = eer * o1i + eei * o1r;
                sr[i1] = sh * p0r + ch * q1r;
                si[i1] = sh * p0i + ch * q1i;
            }
        };

#pragma unroll
        for (int lay = 0; lay < 2; ++lay) {
            const int base = lay * 15;
#pragma unroll
            for (int i = 0; i < 3; ++i) {
                {
                    float th = ap[base + i * 4];
                    float ch, sh; __sincosf(0.5f * th, &sh, &ch);
                    const int m1 = 1 << (3 - i);
                    const int m2 = 1 << (2 - i);
#pragma unroll
                    for (int b0 = 0; b0 < 16; ++b0) {
                        if (b0 & (m1 | m2)) continue;
                        int i00 = b0, i01 = b0 + m2, i10 = b0 + m1, i11 = b0 + m1 + m2;
                        float o00r = sr[i00], o00i = si[i00], o11r = sr[i11], o11i = si[i11];
                        sr[i00] = ch * o00r + sh * o11i;
                        si[i00] = ch * o00i - sh * o11r;
                        sr[i11] = ch * o11r + sh * o00i;
                        si[i11] = ch * o11i - sh * o00r;
                        float o01r = sr[i01], o01i = si[i01], o10r = sr[i10], o10i = si[i10];
                        sr[i01] = ch * o01r + sh * o10i;
                        si[i01] = ch * o01i - sh * o10r;
                        sr[i10] = ch * o10r + sh * o01i;
                        si[i10] = ch * o10i - sh * o01r;
                    }
                }
                u3(i, ap[base + i * 4 + 1], ap[base + i * 4 + 2], ap[base + i * 4 + 3]);
            }
            u3(3, ap[base + 12], ap[base + 13], ap[base + 14]);
        }

        float* orow = out + (row0 + r) * 32;
#pragma unroll
        for (int q = 0; q < 8; ++q) {
            float4 v = make_float4(sr[2 * q], si[2 * q], sr[2 * q + 1], si[2 * q + 1]);
            *reinterpret_cast<float4*>(orow + q * 4) = v;
        }
    }
}

extern "C" void kernel_launch(void* const* d_in, const int* in_sizes, int n_in,
                              void* d_out, int out_size, void* d_ws, size_t ws_size,
                              hipStream_t stream) {
    const float* X  = (const float*)d_in[0];
    const float* W  = (const float*)d_in[1];
    const float* Bv = (const float*)d_in[2];
    float* out = (float*)d_out;

    const int Bn = in_sizes[0] / KDIM;   // 65536
    dim3 grid(Bn / ROWS);                // 1024 blocks x 256 threads
    fused_rnn_circuit<<<grid, NT, 0, stream>>>(X, W, Bv, out);
}